// Round 18
// baseline (59.275 us; speedup 1.0000x reference)
//
#include <hip/hip_runtime.h>

typedef __attribute__((ext_vector_type(8))) short short8v;
typedef __attribute__((ext_vector_type(4))) float f32x4;
typedef __attribute__((ext_vector_type(4))) unsigned u32x4;

// ws float offsets
#define NORM  0               // [2][16][4096] per-slice row inf-norm maxes (f32)
#define H2S   131072          // [4096][20] h2 state
#define AXPF  212992          // [4096] pf * ax[row]
#define PART  217088          // bf16 partials [NS][4096][160] (ushort), from here

__device__ __forceinline__ float fsig(float x){ return 1.0f/(1.0f + __expf(-x)); }
__device__ __forceinline__ float ftanh(float x){ float e = __expf(2.0f*x); return 1.0f - 2.0f/(e+1.0f); }
__device__ __forceinline__ unsigned short f2bf_rne(float f){
  unsigned u = __float_as_uint(f);
  u += 0x7fffu + ((u >> 16) & 1u);
  return (unsigned short)(u >> 16);
}
__device__ __forceinline__ unsigned pack2bf(float lo, float hi){
  unsigned a = __float_as_uint(lo) + 0x8000u;
  unsigned b = __float_as_uint(hi) + 0x8000u;
  return (a >> 16) | (b & 0xFFFF0000u);
}

// GEMM: 64 rowblocks x NS kslices, 512 thr = 8 waves (4 m-tiles x 2 parts).
// NS=16 -> KS=128, single chunk: stage -> one barrier -> 4 ksteps -> write.
// 1024 blocks = 4/CU queued (2 resident) -> inter-block overlap hides stage.
template<int NS>
__global__ __launch_bounds__(512,2) void gemm_kernel(
    const float* __restrict__ x, const float* __restrict__ grad,
    const float* __restrict__ W_ih1, float* __restrict__ ws)
{
  constexpr int KS  = 2048 / NS;
  constexpr int NCH = KS / 128;
  __shared__ unsigned short bs[160*128];   // 40 KB

  const int tid = threadIdx.x;
  const int w = tid >> 6, lane = tid & 63;
  const int mt = w >> 1, gh = w & 1;       // m-tile 0..3, part 0=x 1=grad
  const int m = lane & 15, kg = lane >> 4;
  const int rb = blockIdx.x / NS, ksl = blockIdx.x % NS;
  const int r0 = rb*64;
  const int kb0 = ksl*KS;

  const float* Ap = (gh ? grad : x) + (size_t)(r0 + mt*16 + m)*2048 + kg*8;
  const int xk = (m & 7) << 4;
  const int sg = tid >> 6;                 // stage: 8 gates per q
  const int sp = tid & 63;                 // pair index within 128-col chunk

  f32x4 acc[5];
  #pragma unroll
  for (int t = 0; t < 5; ++t) acc[t] = (f32x4){0.f,0.f,0.f,0.f};
  float vm = 0.f;

  f32x4 a[4][2];
  #pragma unroll
  for (int ks = 0; ks < 4; ++ks) {
    a[ks][0] = __builtin_nontemporal_load((const f32x4*)(Ap + kb0 + ks*32));
    a[ks][1] = __builtin_nontemporal_load((const f32x4*)(Ap + kb0 + ks*32 + 4));
  }

  #pragma unroll
  for (int c = 0; c < NCH; ++c) {
    const int kb = kb0 + c*128;
    #pragma unroll
    for (int q = 0; q < 20; ++q) {
      const int g = q*8 + sg;
      const float* src = W_ih1 + (size_t)((g < 80) ? g : g - 80)*4097
                       + ((g < 80) ? 0 : 2049) + kb + 2*sp;
      const unsigned pk = pack2bf(src[0], src[1]);
      *(unsigned*)((char*)bs + g*256
                   + (((sp >> 2)*16) ^ ((g & 7) << 4)) + (sp & 3)*4) = pk;
    }
    __syncthreads();
    f32x4 an[4][2];
    if (c + 1 < NCH) {
      #pragma unroll
      for (int ks = 0; ks < 4; ++ks) {
        an[ks][0] = __builtin_nontemporal_load((const f32x4*)(Ap + kb + 128 + ks*32));
        an[ks][1] = __builtin_nontemporal_load((const f32x4*)(Ap + kb + 128 + ks*32 + 4));
      }
    }
    #pragma unroll
    for (int ks = 0; ks < 4; ++ks) {
      const f32x4 a0 = a[ks][0], a1 = a[ks][1];
      vm = fmaxf(vm, fmaxf(fmaxf(fabsf(a0.x),fabsf(a0.y)), fmaxf(fabsf(a0.z),fabsf(a0.w))));
      vm = fmaxf(vm, fmaxf(fmaxf(fabsf(a1.x),fabsf(a1.y)), fmaxf(fabsf(a1.z),fabsf(a1.w))));
      union { unsigned u[4]; short8v v; } A_;
      A_.u[0] = pack2bf(a0.x, a0.y);
      A_.u[1] = pack2bf(a0.z, a0.w);
      A_.u[2] = pack2bf(a1.x, a1.y);
      A_.u[3] = pack2bf(a1.z, a1.w);
      const short8v af = A_.v;
      const int kof = (ks*64 + kg*16) ^ xk;
      #pragma unroll
      for (int t = 0; t < 5; ++t) {
        const int lg = gh*80 + t*16 + m;
        const short8v bf = *(const short8v*)((char*)bs + lg*256 + kof);
        acc[t] = __builtin_amdgcn_mfma_f32_16x16x32_bf16(af, bf, acc[t], 0, 0, 0);
      }
    }
    if (c + 1 < NCH) {
      __syncthreads();
      #pragma unroll
      for (int ks = 0; ks < 4; ++ks) { a[ks][0] = an[ks][0]; a[ks][1] = an[ks][1]; }
    }
  }

  vm = fmaxf(vm, __shfl_xor(vm, 16));
  vm = fmaxf(vm, __shfl_xor(vm, 32));
  if (lane < 16)
    ws[NORM + ((size_t)gh*NS + ksl)*4096 + r0 + mt*16 + m] = vm;

  unsigned short* pp = (unsigned short*)(ws + PART)
                     + ((size_t)ksl*4096 + r0 + mt*16 + kg*4)*160 + gh*80 + m;
  #pragma unroll
  for (int t = 0; t < 5; ++t)
    #pragma unroll
    for (int r = 0; r < 4; ++r)
      pp[(size_t)r*160 + t*16] = f2bf_rne(acc[t][r]);
}

// tail: 512 blocks x 256 thr; 8 rows. (256,2) -> 128 VGPR cap.
template<int NS>
__global__ __launch_bounds__(256,2) void tail_kernel(
    const float* __restrict__ loss, const float* __restrict__ W_ih1,
    const float* __restrict__ b_ih1, const float* __restrict__ W_hh1,
    const float* __restrict__ b_hh1, const float* __restrict__ W_ih2,
    const float* __restrict__ b_ih2, const float* __restrict__ W_hh2,
    const float* __restrict__ b_hh2, const float* __restrict__ h1_0,
    const float* __restrict__ h2_0, const float* __restrict__ c1_0,
    const float* __restrict__ c2_0, const float* __restrict__ alpha_raw,
    const int* __restrict__ tptr, const float* ws, float* __restrict__ wsw)
{
  __shared__ float raw[8][160];
  __shared__ float g1[8][80];
  __shared__ float wih2s[1600];
  __shared__ float h1s[8][20];
  __shared__ float c1c[80], c2c[80], lcol[80];
  __shared__ float c10[20], c20[20];
  __shared__ float invX[8], invG[8], lscA[8], axv[8];
  __shared__ float pfs;

  const int tid = threadIdx.x;
  const int r0  = blockIdx.x * 8;

  for (int i = tid; i < 1600; i += 256) wih2s[i] = W_ih2[i];
  if (tid < 20) { c10[tid] = c1_0[tid]; c20[tid] = c2_0[tid]; }
  if (tid < 80) {                                // folded gate-1 constants
    float s = b_ih1[tid] + b_hh1[tid];
    for (int j = 0; j < 20; ++j) s += W_hh1[tid*20+j]*h1_0[j];
    c1c[tid] = s;
  } else if (tid < 160) {                        // folded gate-2 constants
    const int k = tid - 80;
    float s = b_ih2[k] + b_hh2[k];
    for (int j = 0; j < 20; ++j) s += W_hh2[k*20+j]*h2_0[j];
    c2c[k] = s;
  } else if (tid < 240) {                        // loss column of W_ih1
    const int k = tid - 160;
    lcol[k] = W_ih1[(size_t)k*4097 + 2048];
  } else if (tid == 240) {                       // poly factor
    const float tv = (float)(*tptr);
    float pf = 0.f, term = 1.f;
    for (int j = 0; j < 3; ++j) {
      float aa = alpha_raw[j];
      float sp = (aa > 20.f) ? aa : log1pf(__expf(aa));
      pf += sp*term; term *= tv;                 // t^0 == 1 even at t=0
    }
    pfs = pf * powf(0.99f, tv);
  }

  // reduce bf16 partials: 8 rows x 20 groups of 8 gates
  const unsigned short* pbase = (const unsigned short*)(ws + PART);
  if (tid < 160) {
    const int r = tid / 20, c8 = tid - (tid/20)*20;
    float s[8];
    #pragma unroll
    for (int j = 0; j < 8; ++j) s[j] = 0.f;
    #pragma unroll
    for (int sl = 0; sl < NS; ++sl) {
      const u32x4 v = __builtin_nontemporal_load(
          (const u32x4*)(pbase + ((size_t)sl*4096 + r0 + r)*160 + c8*8));
      #pragma unroll
      for (int j = 0; j < 4; ++j) {
        s[2*j]   += __uint_as_float(v[j] << 16);
        s[2*j+1] += __uint_as_float(v[j] & 0xFFFF0000u);
      }
    }
    #pragma unroll
    for (int j = 0; j < 8; ++j) raw[r][c8*8+j] = s[j];
  }
  if (tid < 8) {                                 // norms across slices
    float ax = 0.f, ag = 0.f;
    #pragma unroll
    for (int sl = 0; sl < NS; ++sl) {
      ax = fmaxf(ax, ws[NORM + (size_t)sl*4096 + r0 + tid]);
      ag = fmaxf(ag, ws[NORM + ((size_t)NS + sl)*4096 + r0 + tid]);
    }
    ax = (ax > 0.f) ? ax : 1.0f;  axv[tid] = ax;  invX[tid] = 1.0f/ax;
    ag = (ag > 0.f) ? ag : 1.0f;  invG[tid] = 1.0f/ag;
    float l  = loss[r0 + tid];
    float al = fabsf(l); al = (al > 0.f) ? al : 1.0f;
    lscA[tid] = l / al;
  }
  __syncthreads();

  if (tid < 8) wsw[AXPF + r0 + tid] = pfs * axv[tid];

  for (int q = 0; q < 3; ++q) {                  // gates 1 (8x80)
    const int idx = q*256 + tid;
    if (idx < 640) {
      const int r = idx / 80, k2 = idx - r*80;
      g1[r][k2] = raw[r][k2]*invX[r] + raw[r][80+k2]*invG[r]
                + lcol[k2]*lscA[r] + c1c[k2];
    }
  }
  __syncthreads();

  if (tid < 160) {                               // cell 1
    const int r = tid / 20, j = tid - r*20;
    const float gi = g1[r][j], gf = g1[r][20+j], gc = g1[r][40+j], go = g1[r][60+j];
    const float c1 = fsig(gf)*c10[j] + fsig(gi)*ftanh(gc);
    h1s[r][j] = fsig(go)*ftanh(c1);
  }
  __syncthreads();

  for (int q = 0; q < 3; ++q) {                  // gates 2
    const int idx = q*256 + tid;
    if (idx < 640) {
      const int r = idx / 80, k2 = idx - r*80;
      float s = c2c[k2];
      #pragma unroll
      for (int j = 0; j < 20; ++j) s += wih2s[k2*20+j]*h1s[r][j];
      g1[r][k2] = s;
    }
  }
  __syncthreads();

  if (tid < 160) {                               // cell 2 -> h2 to ws
    const int r = tid / 20, j = tid - r*20;
    const float gi = g1[r][j], gf = g1[r][20+j], gc = g1[r][40+j], go = g1[r][60+j];
    const float c2v = fsig(gf)*c20[j] + fsig(gi)*ftanh(gc);
    wsw[H2S + (size_t)(r0 + r)*20 + j] = fsig(go)*ftanh(c2v);
  }
}

// output GEMM: grid 64 rowblocks x 8 dblocks (per-XCD W_out slice, L2-hot).
__global__ __launch_bounds__(256,4) void outgemm_kernel(
    const float* __restrict__ W_out, const float* __restrict__ b_out,
    const float* ws, float* __restrict__ out)
{
  __shared__ float h2s[64][20];
  __shared__ float axs[64];
  const int tid = threadIdx.x;
  const int db = blockIdx.x & 7, rbk = blockIdx.x >> 3;
  const int row0 = rbk * 64;
  const int d = db*256 + tid;

  for (int i = tid; i < 1280; i += 256) (&h2s[0][0])[i] = ws[H2S + (size_t)row0*20 + i];
  if (tid < 64) axs[tid] = ws[AXPF + row0 + tid];
  __syncthreads();

  const float4* wr = (const float4*)(W_out + (size_t)d*20);
  const float4 w0 = wr[0], w1 = wr[1], w2 = wr[2], w3 = wr[3], w4 = wr[4];
  const float bo = b_out[d];

  #pragma unroll 4
  for (int r = 0; r < 64; ++r) {
    const float4* hp = (const float4*)&h2s[r][0];
    const float4 h0 = hp[0], h1v = hp[1], h2v = hp[2], h3v = hp[3], h4v = hp[4];
    float v = bo;
    v += w0.x*h0.x  + w0.y*h0.y  + w0.z*h0.z  + w0.w*h0.w;
    v += w1.x*h1v.x + w1.y*h1v.y + w1.z*h1v.z + w1.w*h1v.w;
    v += w2.x*h2v.x + w2.y*h2v.y + w2.z*h2v.z + w2.w*h2v.w;
    v += w3.x*h3v.x + w3.y*h3v.y + w3.z*h3v.z + w3.w*h3v.w;
    v += w4.x*h4v.x + w4.y*h4v.y + w4.z*h4v.z + w4.w*h4v.w;
    __builtin_nontemporal_store(axs[r] * ftanh(v),
                                &out[(size_t)(row0+r)*2048 + d]);
  }
}

extern "C" void kernel_launch(void* const* d_in, const int* in_sizes, int n_in,
                              void* d_out, int out_size, void* d_ws, size_t ws_size,
                              hipStream_t stream)
{
  const float* x      = (const float*)d_in[0];
  const float* loss   = (const float*)d_in[1];
  const float* grad   = (const float*)d_in[2];
  const float* W_ih1  = (const float*)d_in[3];
  const float* b_ih1  = (const float*)d_in[4];
  const float* W_hh1  = (const float*)d_in[5];
  const float* b_hh1  = (const float*)d_in[6];
  const float* W_ih2  = (const float*)d_in[7];
  const float* b_ih2  = (const float*)d_in[8];
  const float* W_hh2  = (const float*)d_in[9];
  const float* b_hh2  = (const float*)d_in[10];
  const float* W_out  = (const float*)d_in[11];
  const float* b_out  = (const float*)d_in[12];
  const float* h1_0   = (const float*)d_in[13];
  const float* c1_0   = (const float*)d_in[14];
  const float* h2_0   = (const float*)d_in[15];
  const float* c2_0   = (const float*)d_in[16];
  const float* alpha  = (const float*)d_in[17];
  const int*   t      = (const int*)d_in[18];
  float* ws  = (float*)d_ws;
  float* out = (float*)d_out;

  const size_t base = (size_t)PART * sizeof(float);
  const size_t per_slice = (size_t)4096 * 160 * sizeof(unsigned short);
  if (ws_size >= base + 16*per_slice) {
    hipLaunchKernelGGL(gemm_kernel<16>, dim3(64*16), dim3(512), 0, stream,
                       x, grad, W_ih1, ws);
    hipLaunchKernelGGL(tail_kernel<16>, dim3(512), dim3(256), 0, stream,
                       loss, W_ih1, b_ih1, W_hh1, b_hh1, W_ih2, b_ih2, W_hh2,
                       b_hh2, h1_0, h2_0, c1_0, c2_0, alpha, t, ws, ws);
  } else {
    hipLaunchKernelGGL(gemm_kernel<8>, dim3(64*8), dim3(512), 0, stream,
                       x, grad, W_ih1, ws);
    hipLaunchKernelGGL(tail_kernel<8>, dim3(512), dim3(256), 0, stream,
                       loss, W_ih1, b_ih1, W_hh1, b_hh1, W_ih2, b_ih2, W_hh2,
                       b_hh2, h1_0, h2_0, c1_0, c2_0, alpha, t, ws, ws);
  }
  hipLaunchKernelGGL(outgemm_kernel, dim3(512), dim3(256), 0, stream,
                     W_out, b_out, ws, out);
}

// Round 19
// 53.610 us; speedup vs baseline: 1.1057x; 1.1057x over previous
//
#include <hip/hip_runtime.h>

typedef __attribute__((ext_vector_type(8))) short short8v;
typedef __attribute__((ext_vector_type(4))) float f32x4;
typedef __attribute__((ext_vector_type(4))) unsigned u32x4;

// ws float offsets
#define NORM  0               // [2][8][4096] per-slice row inf-norm maxes (f32)
#define H2S   131072          // [4096][20] h2 state
#define AXPF  212992          // [4096] pf * ax[row]
#define PART  217088          // bf16 partials [NS][4096][160] (ushort), from here

__device__ __forceinline__ float fsig(float x){ return 1.0f/(1.0f + __expf(-x)); }
__device__ __forceinline__ float ftanh(float x){ float e = __expf(2.0f*x); return 1.0f - 2.0f/(e+1.0f); }
__device__ __forceinline__ unsigned short f2bf_rne(float f){
  unsigned u = __float_as_uint(f);
  u += 0x7fffu + ((u >> 16) & 1u);
  return (unsigned short)(u >> 16);
}
__device__ __forceinline__ unsigned pack2bf(float lo, float hi){
  unsigned a = __float_as_uint(lo) + 0x8000u;
  unsigned b = __float_as_uint(hi) + 0x8000u;
  return (a >> 16) | (b & 0xFFFF0000u);
}

// GEMM (R14-proven best): 64 rowblocks x NS kslices, 512 thr = 8 waves.
// B staged from W_ih1 f32->bf16 into swizzled 40KB LDS (ksl<->XCD, L2-hot);
// A fragments upfront + next-chunk prefetch; bf16 partials + exclusive norms.
template<int NS>
__global__ __launch_bounds__(512,2) void gemm_kernel(
    const float* __restrict__ x, const float* __restrict__ grad,
    const float* __restrict__ W_ih1, float* __restrict__ ws)
{
  constexpr int KS  = 2048 / NS;
  constexpr int NCH = KS / 128;
  __shared__ unsigned short bs[160*128];   // 40 KB

  const int tid = threadIdx.x;
  const int w = tid >> 6, lane = tid & 63;
  const int mt = w >> 1, gh = w & 1;       // m-tile 0..3, part 0=x 1=grad
  const int m = lane & 15, kg = lane >> 4;
  const int rb = blockIdx.x / NS, ksl = blockIdx.x % NS;
  const int r0 = rb*64;
  const int kb0 = ksl*KS;

  const float* Ap = (gh ? grad : x) + (size_t)(r0 + mt*16 + m)*2048 + kg*8;
  const int xk = (m & 7) << 4;
  const int sg = tid >> 6;                 // stage: 8 gates per q
  const int sp = tid & 63;                 // pair index within 128-col chunk

  f32x4 acc[5];
  #pragma unroll
  for (int t = 0; t < 5; ++t) acc[t] = (f32x4){0.f,0.f,0.f,0.f};
  float vm = 0.f;

  f32x4 a[4][2];
  #pragma unroll
  for (int ks = 0; ks < 4; ++ks) {
    a[ks][0] = __builtin_nontemporal_load((const f32x4*)(Ap + kb0 + ks*32));
    a[ks][1] = __builtin_nontemporal_load((const f32x4*)(Ap + kb0 + ks*32 + 4));
  }

  #pragma unroll
  for (int c = 0; c < NCH; ++c) {
    const int kb = kb0 + c*128;
    #pragma unroll
    for (int q = 0; q < 20; ++q) {
      const int g = q*8 + sg;
      const float* src = W_ih1 + (size_t)((g < 80) ? g : g - 80)*4097
                       + ((g < 80) ? 0 : 2049) + kb + 2*sp;
      const unsigned pk = pack2bf(src[0], src[1]);
      *(unsigned*)((char*)bs + g*256
                   + (((sp >> 2)*16) ^ ((g & 7) << 4)) + (sp & 3)*4) = pk;
    }
    __syncthreads();
    f32x4 an[4][2];
    if (c + 1 < NCH) {
      #pragma unroll
      for (int ks = 0; ks < 4; ++ks) {
        an[ks][0] = __builtin_nontemporal_load((const f32x4*)(Ap + kb + 128 + ks*32));
        an[ks][1] = __builtin_nontemporal_load((const f32x4*)(Ap + kb + 128 + ks*32 + 4));
      }
    }
    #pragma unroll
    for (int ks = 0; ks < 4; ++ks) {
      const f32x4 a0 = a[ks][0], a1 = a[ks][1];
      vm = fmaxf(vm, fmaxf(fmaxf(fabsf(a0.x),fabsf(a0.y)), fmaxf(fabsf(a0.z),fabsf(a0.w))));
      vm = fmaxf(vm, fmaxf(fmaxf(fabsf(a1.x),fabsf(a1.y)), fmaxf(fabsf(a1.z),fabsf(a1.w))));
      union { unsigned u[4]; short8v v; } A_;
      A_.u[0] = pack2bf(a0.x, a0.y);
      A_.u[1] = pack2bf(a0.z, a0.w);
      A_.u[2] = pack2bf(a1.x, a1.y);
      A_.u[3] = pack2bf(a1.z, a1.w);
      const short8v af = A_.v;
      const int kof = (ks*64 + kg*16) ^ xk;
      #pragma unroll
      for (int t = 0; t < 5; ++t) {
        const int lg = gh*80 + t*16 + m;
        const short8v bf = *(const short8v*)((char*)bs + lg*256 + kof);
        acc[t] = __builtin_amdgcn_mfma_f32_16x16x32_bf16(af, bf, acc[t], 0, 0, 0);
      }
    }
    if (c + 1 < NCH) {
      __syncthreads();
      #pragma unroll
      for (int ks = 0; ks < 4; ++ks) { a[ks][0] = an[ks][0]; a[ks][1] = an[ks][1]; }
    }
  }

  vm = fmaxf(vm, __shfl_xor(vm, 16));
  vm = fmaxf(vm, __shfl_xor(vm, 32));
  if (lane < 16)
    ws[NORM + ((size_t)gh*NS + ksl)*4096 + r0 + mt*16 + m] = vm;

  unsigned short* pp = (unsigned short*)(ws + PART)
                     + ((size_t)ksl*4096 + r0 + mt*16 + kg*4)*160 + gh*80 + m;
  #pragma unroll
  for (int t = 0; t < 5; ++t)
    #pragma unroll
    for (int r = 0; r < 4; ++r)
      pp[(size_t)r*160 + t*16] = f2bf_rne(acc[t][r]);
}

// tail: 512 blocks x 256 thr; 8 rows (R14 exact).
template<int NS>
__global__ __launch_bounds__(256,4) void tail_kernel(
    const float* __restrict__ loss, const float* __restrict__ W_ih1,
    const float* __restrict__ b_ih1, const float* __restrict__ W_hh1,
    const float* __restrict__ b_hh1, const float* __restrict__ W_ih2,
    const float* __restrict__ b_ih2, const float* __restrict__ W_hh2,
    const float* __restrict__ b_hh2, const float* __restrict__ h1_0,
    const float* __restrict__ h2_0, const float* __restrict__ c1_0,
    const float* __restrict__ c2_0, const float* __restrict__ alpha_raw,
    const int* __restrict__ tptr, const float* ws, float* __restrict__ wsw)
{
  __shared__ float raw[8][160];
  __shared__ float g1[8][80];
  __shared__ float wih2s[1600];
  __shared__ float h1s[8][20];
  __shared__ float c1c[80], c2c[80], lcol[80];
  __shared__ float c10[20], c20[20];
  __shared__ float invX[8], invG[8], lscA[8], axv[8];
  __shared__ float pfs;

  const int tid = threadIdx.x;
  const int r0  = blockIdx.x * 8;

  for (int i = tid; i < 1600; i += 256) wih2s[i] = W_ih2[i];
  if (tid < 20) { c10[tid] = c1_0[tid]; c20[tid] = c2_0[tid]; }
  if (tid < 80) {                                // folded gate-1 constants
    float s = b_ih1[tid] + b_hh1[tid];
    for (int j = 0; j < 20; ++j) s += W_hh1[tid*20+j]*h1_0[j];
    c1c[tid] = s;
  } else if (tid < 160) {                        // folded gate-2 constants
    const int k = tid - 80;
    float s = b_ih2[k] + b_hh2[k];
    for (int j = 0; j < 20; ++j) s += W_hh2[k*20+j]*h2_0[j];
    c2c[k] = s;
  } else if (tid < 240) {                        // loss column of W_ih1
    const int k = tid - 160;
    lcol[k] = W_ih1[(size_t)k*4097 + 2048];
  } else if (tid == 240) {                       // poly factor
    const float tv = (float)(*tptr);
    float pf = 0.f, term = 1.f;
    for (int j = 0; j < 3; ++j) {
      float aa = alpha_raw[j];
      float sp = (aa > 20.f) ? aa : log1pf(__expf(aa));
      pf += sp*term; term *= tv;                 // t^0 == 1 even at t=0
    }
    pfs = pf * powf(0.99f, tv);
  }

  // reduce bf16 partials: 8 rows x 20 groups of 8 gates
  const unsigned short* pbase = (const unsigned short*)(ws + PART);
  if (tid < 160) {
    const int r = tid / 20, c8 = tid - (tid/20)*20;
    float s[8];
    #pragma unroll
    for (int j = 0; j < 8; ++j) s[j] = 0.f;
    #pragma unroll
    for (int sl = 0; sl < NS; ++sl) {
      const u32x4 v = __builtin_nontemporal_load(
          (const u32x4*)(pbase + ((size_t)sl*4096 + r0 + r)*160 + c8*8));
      #pragma unroll
      for (int j = 0; j < 4; ++j) {
        s[2*j]   += __uint_as_float(v[j] << 16);
        s[2*j+1] += __uint_as_float(v[j] & 0xFFFF0000u);
      }
    }
    #pragma unroll
    for (int j = 0; j < 8; ++j) raw[r][c8*8+j] = s[j];
  }
  if (tid < 8) {                                 // norms across slices
    float ax = 0.f, ag = 0.f;
    #pragma unroll
    for (int sl = 0; sl < NS; ++sl) {
      ax = fmaxf(ax, ws[NORM + (size_t)sl*4096 + r0 + tid]);
      ag = fmaxf(ag, ws[NORM + ((size_t)NS + sl)*4096 + r0 + tid]);
    }
    ax = (ax > 0.f) ? ax : 1.0f;  axv[tid] = ax;  invX[tid] = 1.0f/ax;
    ag = (ag > 0.f) ? ag : 1.0f;  invG[tid] = 1.0f/ag;
    float l  = loss[r0 + tid];
    float al = fabsf(l); al = (al > 0.f) ? al : 1.0f;
    lscA[tid] = l / al;
  }
  __syncthreads();

  if (tid < 8) wsw[AXPF + r0 + tid] = pfs * axv[tid];

  for (int q = 0; q < 3; ++q) {                  // gates 1 (8x80)
    const int idx = q*256 + tid;
    if (idx < 640) {
      const int r = idx / 80, k2 = idx - r*80;
      g1[r][k2] = raw[r][k2]*invX[r] + raw[r][80+k2]*invG[r]
                + lcol[k2]*lscA[r] + c1c[k2];
    }
  }
  __syncthreads();

  if (tid < 160) {                               // cell 1
    const int r = tid / 20, j = tid - r*20;
    const float gi = g1[r][j], gf = g1[r][20+j], gc = g1[r][40+j], go = g1[r][60+j];
    const float c1 = fsig(gf)*c10[j] + fsig(gi)*ftanh(gc);
    h1s[r][j] = fsig(go)*ftanh(c1);
  }
  __syncthreads();

  for (int q = 0; q < 3; ++q) {                  // gates 2
    const int idx = q*256 + tid;
    if (idx < 640) {
      const int r = idx / 80, k2 = idx - r*80;
      float s = c2c[k2];
      #pragma unroll
      for (int j = 0; j < 20; ++j) s += wih2s[k2*20+j]*h1s[r][j];
      g1[r][k2] = s;
    }
  }
  __syncthreads();

  if (tid < 160) {                               // cell 2 -> h2 to ws
    const int r = tid / 20, j = tid - r*20;
    const float gi = g1[r][j], gf = g1[r][20+j], gc = g1[r][40+j], go = g1[r][60+j];
    const float c2v = fsig(gf)*c20[j] + fsig(gi)*ftanh(gc);
    wsw[H2S + (size_t)(r0 + r)*20 + j] = fsig(go)*ftanh(c2v);
  }
}

// output GEMM: grid 64 rowblocks x 8 dblocks (per-XCD W_out slice, L2-hot).
__global__ __launch_bounds__(256,4) void outgemm_kernel(
    const float* __restrict__ W_out, const float* __restrict__ b_out,
    const float* ws, float* __restrict__ out)
{
  __shared__ float h2s[64][20];
  __shared__ float axs[64];
  const int tid = threadIdx.x;
  const int db = blockIdx.x & 7, rbk = blockIdx.x >> 3;
  const int row0 = rbk * 64;
  const int d = db*256 + tid;

  for (int i = tid; i < 1280; i += 256) (&h2s[0][0])[i] = ws[H2S + (size_t)row0*20 + i];
  if (tid < 64) axs[tid] = ws[AXPF + row0 + tid];
  __syncthreads();

  const float4* wr = (const float4*)(W_out + (size_t)d*20);
  const float4 w0 = wr[0], w1 = wr[1], w2 = wr[2], w3 = wr[3], w4 = wr[4];
  const float bo = b_out[d];

  #pragma unroll 4
  for (int r = 0; r < 64; ++r) {
    const float4* hp = (const float4*)&h2s[r][0];
    const float4 h0 = hp[0], h1v = hp[1], h2v = hp[2], h3v = hp[3], h4v = hp[4];
    float v = bo;
    v += w0.x*h0.x  + w0.y*h0.y  + w0.z*h0.z  + w0.w*h0.w;
    v += w1.x*h1v.x + w1.y*h1v.y + w1.z*h1v.z + w1.w*h1v.w;
    v += w2.x*h2v.x + w2.y*h2v.y + w2.z*h2v.z + w2.w*h2v.w;
    v += w3.x*h3v.x + w3.y*h3v.y + w3.z*h3v.z + w3.w*h3v.w;
    v += w4.x*h4v.x + w4.y*h4v.y + w4.z*h4v.z + w4.w*h4v.w;
    __builtin_nontemporal_store(axs[r] * ftanh(v),
                                &out[(size_t)(row0+r)*2048 + d]);
  }
}

extern "C" void kernel_launch(void* const* d_in, const int* in_sizes, int n_in,
                              void* d_out, int out_size, void* d_ws, size_t ws_size,
                              hipStream_t stream)
{
  const float* x      = (const float*)d_in[0];
  const float* loss   = (const float*)d_in[1];
  const float* grad   = (const float*)d_in[2];
  const float* W_ih1  = (const float*)d_in[3];
  const float* b_ih1  = (const float*)d_in[4];
  const float* W_hh1  = (const float*)d_in[5];
  const float* b_hh1  = (const float*)d_in[6];
  const float* W_ih2  = (const float*)d_in[7];
  const float* b_ih2  = (const float*)d_in[8];
  const float* W_hh2  = (const float*)d_in[9];
  const float* b_hh2  = (const float*)d_in[10];
  const float* W_out  = (const float*)d_in[11];
  const float* b_out  = (const float*)d_in[12];
  const float* h1_0   = (const float*)d_in[13];
  const float* c1_0   = (const float*)d_in[14];
  const float* h2_0   = (const float*)d_in[15];
  const float* c2_0   = (const float*)d_in[16];
  const float* alpha  = (const float*)d_in[17];
  const int*   t      = (const int*)d_in[18];
  float* ws  = (float*)d_ws;
  float* out = (float*)d_out;

  const size_t base = (size_t)PART * sizeof(float);
  const size_t per_slice = (size_t)4096 * 160 * sizeof(unsigned short);
  if (ws_size >= base + 8*per_slice) {
    hipLaunchKernelGGL(gemm_kernel<8>, dim3(64*8), dim3(512), 0, stream,
                       x, grad, W_ih1, ws);
    hipLaunchKernelGGL(tail_kernel<8>, dim3(512), dim3(256), 0, stream,
                       loss, W_ih1, b_ih1, W_hh1, b_hh1, W_ih2, b_ih2, W_hh2,
                       b_hh2, h1_0, h2_0, c1_0, c2_0, alpha, t, ws, ws);
  } else {
    hipLaunchKernelGGL(gemm_kernel<4>, dim3(64*4), dim3(512), 0, stream,
                       x, grad, W_ih1, ws);
    hipLaunchKernelGGL(tail_kernel<4>, dim3(512), dim3(256), 0, stream,
                       loss, W_ih1, b_ih1, W_hh1, b_hh1, W_ih2, b_ih2, W_hh2,
                       b_hh2, h1_0, h2_0, c1_0, c2_0, alpha, t, ws, ws);
  }
  hipLaunchKernelGGL(outgemm_kernel, dim3(512), dim3(256), 0, stream,
                     W_out, b_out, ws, out);
}